// Round 7
// baseline (8565.472 us; speedup 1.0000x reference)
//
#include <hip/hip_runtime.h>

#define TT 512
#define NSTEP 511

typedef _Float16 half8v __attribute__((ext_vector_type(8)));
typedef _Float16 half2v __attribute__((ext_vector_type(2)));
typedef float floatx4 __attribute__((ext_vector_type(4)));

#if __has_builtin(__builtin_amdgcn_exp2f)
#define FAST_EXP2 __builtin_amdgcn_exp2f
#else
#define FAST_EXP2 exp2f
#endif
#if __has_builtin(__builtin_amdgcn_rcpf)
#define FAST_RCP __builtin_amdgcn_rcpf
#else
#define FAST_RCP(x) (1.0f/(x))
#endif

__device__ __forceinline__ float fast_tanh(float x) {
    float e = FAST_EXP2(x * 2.885390081777927f);
    return 1.0f - 2.0f * FAST_RCP(1.0f + e);
}

__device__ __forceinline__ void split_f16(float x, _Float16& hi, _Float16& lo) {
    hi = (_Float16)x;
    lo = (_Float16)(x - (float)hi);
}

__device__ __forceinline__ half2v pack2(float a, float b) {
#if __has_builtin(__builtin_amdgcn_cvt_pkrtz)
    // RTZ rounding — safe because every hi has a matching lo term capturing
    // the residual (hi+lo covers ~20 bits regardless of rounding mode).
    return __builtin_bit_cast(half2v, __builtin_amdgcn_cvt_pkrtz(a, b));
#else
    half2v r; r[0] = (_Float16)a; r[1] = (_Float16)b; return r;
#endif
}

// Block = 128 threads = 2 waves; each block integrates TWO 16-batch tiles
// (2-tile ILP per wave: independent chains hide LDS/MFMA latency).
// Wave w owns M-rows [32w,32w+32) of layers 1/2 and rows [16w,16w+16) of
// layer 3 / state z. Weights/biases shared across tiles.
// A-frag: A[m=lane&15][k=quad*8+j]; B-frag: B[k=quad*8+j][n=lane&15];
// C: col(N)=lane&15, row(M)=quad*4+reg.
// Precision: 3-way hi/lo f16 split everywhere (R3-proven):
//   W*x ~= Whi*xhi + Wlo*xhi + Whi*xlo, fp32 accumulate.
// R7 isolation experiment: __syncthreads() everywhere (the R5/R6 inline-asm
// lds_barrier is the suspected race source — both lds_barrier builds failed
// nondeterministically, every __syncthreads build passed).
__global__ __launch_bounds__(128, 2)
void cde_fused(const float* __restrict__ times,
               const float* __restrict__ grads,   // (B, T, 3)
               const float* __restrict__ w1, const float* __restrict__ b1,
               const float* __restrict__ w2, const float* __restrict__ b2,
               const float* __restrict__ w3, const float* __restrict__ b3,
               const float* __restrict__ w_enc, const float* __restrict__ b_enc,
               const float* __restrict__ w_ro, const float* __restrict__ b_ro,
               float* __restrict__ out)
{
    const int tid  = threadIdx.x;      // 0..127
    const int wid  = tid >> 6;         // wave id: 0,1
    const int lane = tid & 63;
    const int col  = lane & 15;
    const int quad = lane >> 4;
    const int base = blockIdx.x << 5;  // 32 batch per block

    __shared__ __align__(16) _Float16 zbufH[2][16][40];
    __shared__ __align__(16) _Float16 zbufL[2][16][40];
    __shared__ __align__(16) _Float16 h1bufH[2][16][72];
    __shared__ __align__(16) _Float16 h1bufL[2][16][72];
    __shared__ __align__(16) _Float16 h2bufH[2][16][72];
    __shared__ __align__(16) _Float16 h2bufL[2][16][72];
    __shared__ __align__(16) float    dqbuf[2][16][4];
    __shared__ __align__(16) float    robuf[2][16];

    // -------- weights -> f16 hi/lo A-fragments (this wave's halves) ---------
    half8v w1fH[2], w1fL[2], w2fH[2][2], w2fL[2][2], w3fH[3][2], w3fL[3][2];
    #pragma unroll
    for (int mt = 0; mt < 2; ++mt) {
        const int T = 2*wid + mt;
        const float* p = w1 + (16*T + col)*32 + quad*8;
        #pragma unroll
        for (int j = 0; j < 8; ++j) {
            _Float16 hi, lo; split_f16(p[j], hi, lo);
            w1fH[mt][j] = hi; w1fL[mt][j] = lo;
        }
    }
    #pragma unroll
    for (int mt = 0; mt < 2; ++mt) {
        const int T = 2*wid + mt;
        #pragma unroll
        for (int kt = 0; kt < 2; ++kt) {
            const float* p = w2 + (16*T + col)*64 + kt*32 + quad*8;
            #pragma unroll
            for (int j = 0; j < 8; ++j) {
                _Float16 hi, lo; split_f16(p[j], hi, lo);
                w2fH[mt][kt][j] = hi; w2fL[mt][kt][j] = lo;
            }
        }
    }
    #pragma unroll
    for (int c = 0; c < 3; ++c) {
        const int row = (16*wid + col)*3 + c;
        #pragma unroll
        for (int kt = 0; kt < 2; ++kt) {
            const float* p = w3 + row*64 + kt*32 + quad*8;
            #pragma unroll
            for (int j = 0; j < 8; ++j) {
                _Float16 hi, lo; split_f16(p[j], hi, lo);
                w3fH[c][kt][j] = hi; w3fL[c][kt][j] = lo;
            }
        }
    }

    // biases in C-layout
    float b1c[2][4], b2c[2][4], b3c[3][4];
    #pragma unroll
    for (int mt = 0; mt < 2; ++mt) {
        const int T = 2*wid + mt;
        #pragma unroll
        for (int r = 0; r < 4; ++r) {
            b1c[mt][r] = b1[16*T + 4*quad + r];
            b2c[mt][r] = b2[16*T + 4*quad + r];
        }
    }
    #pragma unroll
    for (int c = 0; c < 3; ++c)
        #pragma unroll
        for (int r = 0; r < 4; ++r)
            b3c[c][r] = b3[(16*wid + 4*quad + r)*3 + c];

    // state z rows owned by this wave: h = 16*wid + 4*quad + r; per tile
    float z[2][4];
    #pragma unroll
    for (int r = 0; r < 4; ++r) {
        const int h = 16*wid + 4*quad + r;
        const float z0 = w_enc[h] + b_enc[h];
        z[0][r] = z0; z[1][r] = z0;
    }
    const float dt = times[1] - times[0];

    // dq staging: threads 0..95 each own one (tile,b,c) stream
    const bool dqact = tid < 96;
    const int lcl = dqact ? tid : 0;
    const int tl  = lcl / 48;
    const int idx = lcl - 48*tl;
    const int bl  = idx / 3;
    const int cc  = idx - 3*bl;
    const float* gp = grads + (long)(base + 16*tl + bl)*(TT*3) + cc;
    float dqreg = gp[0];

    static constexpr float AT[6][5] = {
        {0.f, 0.f, 0.f, 0.f, 0.f},
        {0.161f, 0.f, 0.f, 0.f, 0.f},
        {-0.008480655492356989f, 0.335480655492357f, 0.f, 0.f, 0.f},
        {2.8971530571054935f, -6.359448489975075f, 4.3622954328695815f, 0.f, 0.f},
        {5.325864828439257f, -11.748883564062828f, 7.4955393428898365f,
         -0.09249506636175525f, 0.f},
        {5.86145544294642f, -12.92096931784711f, 8.159367898576159f,
         -0.071584973281401f, -0.028269050394068383f}};
    static constexpr float BT[6] = {
        0.09646076681806523f, 0.01f, 0.4798896504144996f, 1.379008574103742f,
        -3.290069515436081f, 2.324710524099774f};

    float kk[2][6][4];
    float dq[2][3];

    for (int n = 0; n < NSTEP; ++n) {
        if (dqact) dqbuf[tl][bl][cc] = dqreg * dt;

        #pragma unroll
        for (int s = 0; s < 6; ++s) {
            // ---- stage za (both tiles), 3-way split, store to LDS ----
            #pragma unroll
            for (int t = 0; t < 2; ++t) {
                float za[4];
                #pragma unroll
                for (int r = 0; r < 4; ++r) {
                    float v = z[t][r];
                    #pragma unroll
                    for (int j = 0; j < s; ++j) v += AT[s][j] * kk[t][j][r];
                    za[r] = v;
                }
                union { half2v h2[2]; uint2 u; } pkH, pkL;
                pkH.h2[0] = pack2(za[0], za[1]);
                pkH.h2[1] = pack2(za[2], za[3]);
                pkL.h2[0] = pack2(za[0] - (float)pkH.h2[0][0],
                                  za[1] - (float)pkH.h2[0][1]);
                pkL.h2[1] = pack2(za[2] - (float)pkH.h2[1][0],
                                  za[3] - (float)pkH.h2[1][1]);
                *(uint2*)&zbufH[t][col][16*wid + 4*quad] = pkH.u;
                *(uint2*)&zbufL[t][col][16*wid + 4*quad] = pkL.u;
            }
            __syncthreads();
            if (s == 0) {
                #pragma unroll
                for (int t = 0; t < 2; ++t) {
                    const float4 dv = *(const float4*)&dqbuf[t][col][0];
                    dq[t][0] = dv.x; dq[t][1] = dv.y; dq[t][2] = dv.z;
                }
                const int nn = (n + 1 < NSTEP) ? (n + 1) : (NSTEP - 1);
                dqreg = gp[nn * 3];          // prefetch next step
            }

            // ---- layer 1: this wave's 32 rows, both tiles ----
            #pragma unroll
            for (int t = 0; t < 2; ++t) {
                const half8v zfH = *(const half8v*)&zbufH[t][col][quad*8];
                const half8v zfL = *(const half8v*)&zbufL[t][col][quad*8];
                #pragma unroll
                for (int mt = 0; mt < 2; ++mt) {
                    floatx4 acc = {b1c[mt][0], b1c[mt][1], b1c[mt][2], b1c[mt][3]};
                    acc = __builtin_amdgcn_mfma_f32_16x16x32_f16(w1fH[mt], zfH, acc, 0, 0, 0);
                    acc = __builtin_amdgcn_mfma_f32_16x16x32_f16(w1fL[mt], zfH, acc, 0, 0, 0);
                    acc = __builtin_amdgcn_mfma_f32_16x16x32_f16(w1fH[mt], zfL, acc, 0, 0, 0);
                    float th[4];
                    #pragma unroll
                    for (int r = 0; r < 4; ++r) th[r] = fast_tanh(acc[r]);
                    union { half2v h2[2]; uint2 u; } pkH, pkL;
                    pkH.h2[0] = pack2(th[0], th[1]);
                    pkH.h2[1] = pack2(th[2], th[3]);
                    pkL.h2[0] = pack2(th[0] - (float)pkH.h2[0][0],
                                      th[1] - (float)pkH.h2[0][1]);
                    pkL.h2[1] = pack2(th[2] - (float)pkH.h2[1][0],
                                      th[3] - (float)pkH.h2[1][1]);
                    *(uint2*)&h1bufH[t][col][32*wid + 16*mt + 4*quad] = pkH.u;
                    *(uint2*)&h1bufL[t][col][32*wid + 16*mt + 4*quad] = pkL.u;
                }
            }
            __syncthreads();

            // ---- layer 2: this wave's 32 rows, both tiles ----
            #pragma unroll
            for (int t = 0; t < 2; ++t) {
                const half8v h1f0H = *(const half8v*)&h1bufH[t][col][quad*8];
                const half8v h1f1H = *(const half8v*)&h1bufH[t][col][32 + quad*8];
                const half8v h1f0L = *(const half8v*)&h1bufL[t][col][quad*8];
                const half8v h1f1L = *(const half8v*)&h1bufL[t][col][32 + quad*8];
                #pragma unroll
                for (int mt = 0; mt < 2; ++mt) {
                    floatx4 acc = {b2c[mt][0], b2c[mt][1], b2c[mt][2], b2c[mt][3]};
                    acc = __builtin_amdgcn_mfma_f32_16x16x32_f16(w2fH[mt][0], h1f0H, acc, 0, 0, 0);
                    acc = __builtin_amdgcn_mfma_f32_16x16x32_f16(w2fL[mt][0], h1f0H, acc, 0, 0, 0);
                    acc = __builtin_amdgcn_mfma_f32_16x16x32_f16(w2fH[mt][0], h1f0L, acc, 0, 0, 0);
                    acc = __builtin_amdgcn_mfma_f32_16x16x32_f16(w2fH[mt][1], h1f1H, acc, 0, 0, 0);
                    acc = __builtin_amdgcn_mfma_f32_16x16x32_f16(w2fL[mt][1], h1f1H, acc, 0, 0, 0);
                    acc = __builtin_amdgcn_mfma_f32_16x16x32_f16(w2fH[mt][1], h1f1L, acc, 0, 0, 0);
                    float th[4];
                    #pragma unroll
                    for (int r = 0; r < 4; ++r) th[r] = fast_tanh(acc[r]);
                    union { half2v h2[2]; uint2 u; } pkH, pkL;
                    pkH.h2[0] = pack2(th[0], th[1]);
                    pkH.h2[1] = pack2(th[2], th[3]);
                    pkL.h2[0] = pack2(th[0] - (float)pkH.h2[0][0],
                                      th[1] - (float)pkH.h2[0][1]);
                    pkL.h2[1] = pack2(th[2] - (float)pkH.h2[1][0],
                                      th[3] - (float)pkH.h2[1][1]);
                    *(uint2*)&h2bufH[t][col][32*wid + 16*mt + 4*quad] = pkH.u;
                    *(uint2*)&h2bufL[t][col][32*wid + 16*mt + 4*quad] = pkL.u;
                }
            }
            __syncthreads();

            // ---- layer 3: c = 0..2 of this wave's half, both tiles ----
            #pragma unroll
            for (int t = 0; t < 2; ++t) {
                const half8v h2f0H = *(const half8v*)&h2bufH[t][col][quad*8];
                const half8v h2f1H = *(const half8v*)&h2bufH[t][col][32 + quad*8];
                const half8v h2f0L = *(const half8v*)&h2bufL[t][col][quad*8];
                const half8v h2f1L = *(const half8v*)&h2bufL[t][col][32 + quad*8];
                float a3[3][4];
                #pragma unroll
                for (int c = 0; c < 3; ++c) {
                    floatx4 acc = {b3c[c][0], b3c[c][1], b3c[c][2], b3c[c][3]};
                    acc = __builtin_amdgcn_mfma_f32_16x16x32_f16(w3fH[c][0], h2f0H, acc, 0, 0, 0);
                    acc = __builtin_amdgcn_mfma_f32_16x16x32_f16(w3fL[c][0], h2f0H, acc, 0, 0, 0);
                    acc = __builtin_amdgcn_mfma_f32_16x16x32_f16(w3fH[c][0], h2f0L, acc, 0, 0, 0);
                    acc = __builtin_amdgcn_mfma_f32_16x16x32_f16(w3fH[c][1], h2f1H, acc, 0, 0, 0);
                    acc = __builtin_amdgcn_mfma_f32_16x16x32_f16(w3fL[c][1], h2f1H, acc, 0, 0, 0);
                    acc = __builtin_amdgcn_mfma_f32_16x16x32_f16(w3fH[c][1], h2f1L, acc, 0, 0, 0);
                    #pragma unroll
                    for (int r = 0; r < 4; ++r) a3[c][r] = acc[r];
                }
                #pragma unroll
                for (int r = 0; r < 4; ++r)
                    kk[t][s][r] = a3[0][r]*dq[t][0] + a3[1][r]*dq[t][1]
                                + a3[2][r]*dq[t][2];
            }
            // NOTE: no barrier needed here — next stage's zbuf writes don't
            // alias h2buf, and zbuf reads are 1 barrier after its writes.
        }

        // z += sum_i B_i * k_i
        #pragma unroll
        for (int t = 0; t < 2; ++t)
            #pragma unroll
            for (int r = 0; r < 4; ++r) {
                float v = z[t][r];
                #pragma unroll
                for (int j = 0; j < 6; ++j) v += BT[j] * kk[t][j][r];
                z[t][r] = v;
            }
    }

    // ---- readout: logit[b] = sum_h z[h][b]*w_ro[h] + b_ro; out = sigmoid ----
    #pragma unroll
    for (int t = 0; t < 2; ++t) {
        float part = 0.f;
        #pragma unroll
        for (int r = 0; r < 4; ++r)
            part += z[t][r] * w_ro[16*wid + 4*quad + r];
        part += __shfl_xor(part, 16, 64);
        part += __shfl_xor(part, 32, 64);
        if (wid == 1 && lane < 16) robuf[t][col] = part;
        __syncthreads();
        if (wid == 0 && lane < 16) {
            const float x = part + robuf[t][col] + b_ro[0];
            out[base + 16*t + col] = FAST_RCP(1.0f + FAST_EXP2(-1.4426950408889634f * x));
        }
    }
}

extern "C" void kernel_launch(void* const* d_in, const int* in_sizes, int n_in,
                              void* d_out, int out_size, void* d_ws, size_t ws_size,
                              hipStream_t stream) {
    const float* times = (const float*)d_in[0];
    const float* grads = (const float*)d_in[1];
    const float* w1    = (const float*)d_in[2];
    const float* b1    = (const float*)d_in[3];
    const float* w2    = (const float*)d_in[4];
    const float* b2    = (const float*)d_in[5];
    const float* w3    = (const float*)d_in[6];
    const float* b3    = (const float*)d_in[7];
    const float* w_enc = (const float*)d_in[8];
    const float* b_enc = (const float*)d_in[9];
    const float* w_ro  = (const float*)d_in[10];
    const float* b_ro  = (const float*)d_in[11];

    const int B = in_sizes[1] / (TT * 3);   // 16384
    dim3 grid(B / 32), block(128);
    hipLaunchKernelGGL(cde_fused, grid, block, 0, stream,
                       times, grads, w1, b1, w2, b2, w3, b3,
                       w_enc, b_enc, w_ro, b_ro, (float*)d_out);
}